// Round 1
// baseline (140.511 us; speedup 1.0000x reference)
//
#include <hip/hip_runtime.h>
#include <math.h>

// CapsuleLinear dynamic routing, restructured so `priors` is never materialized.
//   s[b,o,i]   = sum_n prob[b,o,n] * x[b,n,i]
//   out[b,o,l] = sum_i W[o,l,i] * s[b,o,i]
//   logits[b,o,n] = x[b,n,:] . T[b,o,:],  T accumulates t_r[o,i] = sum_l W[o,l,i]*v_r[o,l]
// Chain: k_init -> k_pass -> k_vt -> k_pass -> k_vt(final)

#define N_B      32
#define IN_CAPS  1152
#define IN_LEN   32
#define OUT_CAPS 64
#define OUT_LEN  32

#define NCHUNK 16                    // n-chunks per batch -> 32*16 = 512 blocks
#define NPB    (IN_CAPS / NCHUNK)    // 72 n per block
#define PASS_WAVES 4                 // 256-thread blocks
#define NPW    (NPB / PASS_WAVES)    // 18 n per wave

// ---------------------------------------------------------------------------
// k_init: s0[i] = (1/64) sum_n x[b,n,i]; u = W@s0; v0 = squash(u); T = W^T@v0
// ---------------------------------------------------------------------------
__global__ __launch_bounds__(256) void k_init(const float* __restrict__ x,
                                              const float* __restrict__ W,
                                              float* __restrict__ T) {
    const int b   = blockIdx.x;
    const int tid = threadIdx.x;
    const float* xb = x + (size_t)b * IN_CAPS * IN_LEN;

    // --- reduce x over n (coalesced float4) ---
    __shared__ float4 red4[32][8];
    {
        const int q = tid & 7;        // float4 column (8 per row of 32)
        const int g = tid >> 3;       // 0..31 n-offset
        float4 acc = make_float4(0.f, 0.f, 0.f, 0.f);
        for (int n = g; n < IN_CAPS; n += 32) {
            const float4 v = *(const float4*)(xb + n * IN_LEN + q * 4);
            acc.x += v.x; acc.y += v.y; acc.z += v.z; acc.w += v.w;
        }
        red4[g][q] = acc;
    }
    __syncthreads();
    __shared__ float s0[IN_LEN];
    if (tid < 8) {
        float4 v = make_float4(0.f, 0.f, 0.f, 0.f);
        for (int g = 0; g < 32; ++g) {
            const float4 r = red4[g][tid];
            v.x += r.x; v.y += r.y; v.z += r.z; v.w += r.w;
        }
        const float inv = 1.f / 64.f;   // uniform softmax prob at r=0
        s0[tid * 4 + 0] = v.x * inv;
        s0[tid * 4 + 1] = v.y * inv;
        s0[tid * 4 + 2] = v.z * inv;
        s0[tid * 4 + 3] = v.w * inv;
    }
    __syncthreads();

    // --- u[o][l] = sum_i W[o,l,i] * s0[i] ---
    __shared__ float u[OUT_CAPS * OUT_LEN];
    for (int e = tid; e < OUT_CAPS * OUT_LEN; e += 256) {
        const float* wrow = W + (size_t)e * IN_LEN;
        float a = 0.f;
#pragma unroll
        for (int i = 0; i < IN_LEN; ++i) a = fmaf(wrow[i], s0[i], a);
        u[e] = a;
    }
    __syncthreads();

    // --- squash scale per o ---
    __shared__ float scale[OUT_CAPS];
    if (tid < OUT_CAPS) {
        float ns = 0.f;
#pragma unroll
        for (int l = 0; l < OUT_LEN; ++l) { const float v = u[tid * OUT_LEN + l]; ns = fmaf(v, v, ns); }
        scale[tid] = sqrtf(ns) / (1.f + ns);
    }
    __syncthreads();

    // --- T[b,o,i] = sum_l W[o,l,i] * (u[o,l]*scale[o]) ---
    for (int e = tid; e < OUT_CAPS * IN_LEN; e += 256) {
        const int o = e >> 5, i = e & 31;
        float a = 0.f;
#pragma unroll
        for (int l = 0; l < OUT_LEN; ++l)
            a = fmaf(W[((size_t)o * OUT_LEN + l) * IN_LEN + i], u[o * OUT_LEN + l], a);
        T[(size_t)b * OUT_CAPS * IN_LEN + e] = a * scale[o];
    }
}

// ---------------------------------------------------------------------------
// k_pass: per (b, n-chunk): logit[o]=x.T[o]; softmax over o (one wave, lane=o);
//         s_partial[o,i] += prob[o]*x[i]  (registers) -> flush to part[b,c,:]
// ---------------------------------------------------------------------------
__global__ __launch_bounds__(256) void k_pass(const float* __restrict__ x,
                                              const float* __restrict__ T,
                                              float* __restrict__ part) {
    const int b    = blockIdx.x >> 4;     // / NCHUNK
    const int c    = blockIdx.x & (NCHUNK - 1);
    const int lane = threadIdx.x & 63;    // = output capsule o
    const int wave = __builtin_amdgcn_readfirstlane(threadIdx.x >> 6);

    // lane-private T row and s accumulator (32 VGPRs each)
    float t[IN_LEN], s[IN_LEN];
    {
        const float* Trow = T + ((size_t)b * OUT_CAPS + lane) * IN_LEN;
#pragma unroll
        for (int i = 0; i < IN_LEN; ++i) { t[i] = Trow[i]; s[i] = 0.f; }
    }

    const float* xb = x + ((size_t)b * IN_CAPS + c * NPB + wave * NPW) * IN_LEN;
    for (int j = 0; j < NPW; ++j) {
        const float* xn = xb + j * IN_LEN;   // wave-uniform address
        float xv[IN_LEN];
#pragma unroll
        for (int i = 0; i < IN_LEN; ++i) xv[i] = xn[i];

        float logit = 0.f;
#pragma unroll
        for (int i = 0; i < IN_LEN; ++i) logit = fmaf(xv[i], t[i], logit);

        // softmax over the 64 lanes (= 64 output capsules)
        float m = logit;
#pragma unroll
        for (int off = 32; off >= 1; off >>= 1) m = fmaxf(m, __shfl_xor(m, off, 64));
        const float p = __expf(logit - m);
        float sum = p;
#pragma unroll
        for (int off = 32; off >= 1; off >>= 1) sum += __shfl_xor(sum, off, 64);
        const float prob = p / sum;

#pragma unroll
        for (int i = 0; i < IN_LEN; ++i) s[i] = fmaf(prob, xv[i], s[i]);
    }

    // reduce the 4 wave partials via LDS, write block partial to global
    __shared__ __align__(16) float sp[PASS_WAVES * OUT_CAPS * IN_LEN]; // 32 KB
    {
        float4* dst = (float4*)&sp[(wave * OUT_CAPS + lane) * IN_LEN];
#pragma unroll
        for (int q = 0; q < 8; ++q)
            dst[q] = make_float4(s[4 * q], s[4 * q + 1], s[4 * q + 2], s[4 * q + 3]);
    }
    __syncthreads();
    {
        const float4* sp4 = (const float4*)sp;
        float4* pb4 = (float4*)(part + ((size_t)b * NCHUNK + c) * OUT_CAPS * IN_LEN);
        for (int e = threadIdx.x; e < OUT_CAPS * IN_LEN / 4; e += 256) {
            const float4 a0 = sp4[e];
            const float4 a1 = sp4[512 + e];
            const float4 a2 = sp4[1024 + e];
            const float4 a3 = sp4[1536 + e];
            pb4[e] = make_float4(a0.x + a1.x + a2.x + a3.x,
                                 a0.y + a1.y + a2.y + a3.y,
                                 a0.z + a1.z + a2.z + a3.z,
                                 a0.w + a1.w + a2.w + a3.w);
        }
    }
}

// ---------------------------------------------------------------------------
// k_vt: s = sum_c part; u = W@s; squash; if final -> write out,
//       else T += W^T @ v
// ---------------------------------------------------------------------------
__global__ __launch_bounds__(256) void k_vt(const float* __restrict__ W,
                                            const float* __restrict__ part,
                                            float* __restrict__ T,
                                            float* __restrict__ out,
                                            int final_iter) {
    const int b   = blockIdx.x;
    const int tid = threadIdx.x;

    __shared__ float s_lds[OUT_CAPS * IN_LEN];
    {
        const float4* pb4 = (const float4*)(part + (size_t)b * NCHUNK * OUT_CAPS * IN_LEN);
        for (int e = tid; e < OUT_CAPS * IN_LEN / 4; e += 256) {
            float4 acc = make_float4(0.f, 0.f, 0.f, 0.f);
#pragma unroll
            for (int c = 0; c < NCHUNK; ++c) {
                const float4 v = pb4[c * (OUT_CAPS * IN_LEN / 4) + e];
                acc.x += v.x; acc.y += v.y; acc.z += v.z; acc.w += v.w;
            }
            ((float4*)s_lds)[e] = acc;
        }
    }
    __syncthreads();

    __shared__ float u[OUT_CAPS * OUT_LEN];
    for (int e = tid; e < OUT_CAPS * OUT_LEN; e += 256) {
        const int o = e >> 5;
        const float* wrow = W + (size_t)e * IN_LEN;
        const float* srow = s_lds + o * IN_LEN;
        float a = 0.f;
#pragma unroll
        for (int i = 0; i < IN_LEN; ++i) a = fmaf(wrow[i], srow[i], a);
        u[e] = a;
    }
    __syncthreads();

    __shared__ float scale[OUT_CAPS];
    if (tid < OUT_CAPS) {
        float ns = 0.f;
#pragma unroll
        for (int l = 0; l < OUT_LEN; ++l) { const float v = u[tid * OUT_LEN + l]; ns = fmaf(v, v, ns); }
        scale[tid] = sqrtf(ns) / (1.f + ns);
    }
    __syncthreads();

    if (final_iter) {
        for (int e = tid; e < OUT_CAPS * OUT_LEN; e += 256)
            out[(size_t)b * OUT_CAPS * OUT_LEN + e] = u[e] * scale[e >> 5];
    } else {
        for (int e = tid; e < OUT_CAPS * IN_LEN; e += 256) {
            const int o = e >> 5, i = e & 31;
            float a = 0.f;
#pragma unroll
            for (int l = 0; l < OUT_LEN; ++l)
                a = fmaf(W[((size_t)o * OUT_LEN + l) * IN_LEN + i], u[o * OUT_LEN + l], a);
            T[(size_t)b * OUT_CAPS * IN_LEN + e] += a * scale[o];
        }
    }
}

extern "C" void kernel_launch(void* const* d_in, const int* in_sizes, int n_in,
                              void* d_out, int out_size, void* d_ws, size_t ws_size,
                              hipStream_t stream) {
    const float* x = (const float*)d_in[0];   // [32,1152,32]
    const float* W = (const float*)d_in[1];   // [64,32,32]
    float* out = (float*)d_out;               // [32,64,32]

    float* T    = (float*)d_ws;                         // 32*64*32 floats (256 KB)
    float* part = T + (size_t)N_B * OUT_CAPS * IN_LEN;  // 32*16*64*32 floats (4 MB)

    k_init<<<N_B, 256, 0, stream>>>(x, W, T);
    k_pass<<<N_B * NCHUNK, 256, 0, stream>>>(x, T, part);        // routing iter 1
    k_vt  <<<N_B, 256, 0, stream>>>(W, part, T, out, 0);
    k_pass<<<N_B * NCHUNK, 256, 0, stream>>>(x, T, part);        // routing iter 2
    k_vt  <<<N_B, 256, 0, stream>>>(W, part, T, out, 1);
}